// Round 1
// baseline (446.209 us; speedup 1.0000x reference)
//
#include <hip/hip_runtime.h>
#include <cstdint>
#include <cstddef>

// ---------------- problem constants ----------------
#define BB 8
#define SS 4096
#define DI 1024
#define DH 1024
#define MDIM (BB * SS)      // 32768
#define NC 128              // scan chunks per sequence
#define CL 32               // chunk length (NC*CL == SS)

// ---------------- ws layout (bytes) ----------------
static constexpr size_t OFF_XB   = 0;                         // 64MB
static constexpr size_t OFF_WZB  = 67108864;                  // 2MB
static constexpr size_t OFF_WHB  = OFF_WZB + 2097152;         // 2MB
static constexpr size_t OFF_K    = OFF_WHB + 2097152;         // 64MB fp16 gate preact k
static constexpr size_t OFF_P    = OFF_K + 67108864;          // 64MB fp16 candidate preact
static constexpr size_t OFF_CLA  = 0;                         // overlay (4MB)
static constexpr size_t OFF_CLB  = 4194304;
static constexpr size_t OFF_CAR  = 8388608;

typedef __bf16 bf16;
typedef _Float16 fp16;
typedef short short8 __attribute__((ext_vector_type(8)));
typedef float f4 __attribute__((ext_vector_type(4)));
typedef float f32x8 __attribute__((ext_vector_type(8)));
typedef bf16 bf16x8 __attribute__((ext_vector_type(8)));
typedef fp16 h4 __attribute__((ext_vector_type(4)));

// ---------------- fp32 -> bf16 conversion ----------------
__global__ void convert_kernel(const float* __restrict__ x, const float* __restrict__ wz,
                               const float* __restrict__ wh,
                               bf16* __restrict__ xb, bf16* __restrict__ wzb, bf16* __restrict__ whb) {
    size_t i = ((size_t)blockIdx.x * 256 + threadIdx.x) * 8;
    const float* src; bf16* dst; size_t off;
    if (i < 33554432u) { src = x; dst = xb; off = i; }
    else if (i < 33554432u + 1048576u) { src = wz; dst = wzb; off = i - 33554432u; }
    else { src = wh; dst = whb; off = i - 34603008u; }
    f32x8 v = *(const f32x8*)(src + off);
    bf16x8 o = __builtin_convertvector(v, bf16x8);
    *(bf16x8*)(dst + off) = o;
}

// ---------------- async global->LDS (16B per lane) ----------------
__device__ __forceinline__ void gload_lds16(const void* g, void* l) {
    __builtin_amdgcn_global_load_lds((const __attribute__((address_space(1))) void*)g,
                                     (__attribute__((address_space(3))) void*)l, 16, 0, 0);
}

// raw barrier: no vmcnt/lgkmcnt drain (unlike __syncthreads); asm clobbers pin
// compiler memory-op ordering across it.
__device__ __forceinline__ void pbar() {
    asm volatile("" ::: "memory");
    __builtin_amdgcn_s_barrier();
    asm volatile("" ::: "memory");
}

// ================= 256x256 8-phase GEMM (T2+T3+T4+T5) =================
// LDS: 8 units of 16KB: buf d in [d*64K, +64K): A kh0@+0, A kh1@+16K, B kh0@+32K, B kh1@+48K.
// Unit layout: 256 rows x 32 bf16 (64B rows), st_16x32 swizzled: LDS(row,c)=global(row, c ^ ((row&8)?32:0)).
// gload_lds dest is linear (required); swizzle applied on the global SOURCE lane column and on reads.
__device__ __forceinline__ void stage_unit(const bf16* __restrict__ src, int row0, char* dst,
                                           int col0 /*elements*/, int w, int l) {
    const int cs = ((l & 3) ^ ((l >> 4) & 2)) << 4;   // pre-swizzled source col-byte
    const int r = row0 + w * 32 + (l >> 2);
    gload_lds16((const char*)(src + (size_t)r * DI + col0) + cs, dst + w * 2048 + l * 16);
    gload_lds16((const char*)(src + (size_t)(r + 16) * DI + col0) + cs, dst + w * 2048 + 1024 + l * 16);
}

__device__ __forceinline__ void read_a4(short8 (&af)[4], const char* base, int wr, int mf0, int l) {
    const char* p = base + (wr * 128 + mf0 * 16 + (l & 15)) * 64 + (((l >> 4) << 4) ^ ((l & 8) << 2));
#pragma unroll
    for (int i = 0; i < 4; i++) af[i] = *(const short8*)(p + i * 1024);
}

__device__ __forceinline__ void read_b4(short8 (&bf)[4], const char* base, int wc, int l) {
    const char* p = base + (wc * 64 + (l & 15)) * 64 + (((l >> 4) << 4) ^ ((l & 8) << 2));
#pragma unroll
    for (int j = 0; j < 4; j++) bf[j] = *(const short8*)(p + j * 1024);
}

template<int MF0>
__device__ __forceinline__ void mfma16(const short8 (&af)[4], const short8 (&bf)[4], f4 (&acc)[8][4]) {
    __builtin_amdgcn_s_setprio(1);          // T5
#pragma unroll
    for (int i = 0; i < 4; i++)
#pragma unroll
        for (int j = 0; j < 4; j++)
            acc[MF0 + i][j] = __builtin_amdgcn_mfma_f32_16x16x32_bf16(af[i], bf[j], acc[MF0 + i][j], 0, 0, 0);
    __builtin_amdgcn_s_setprio(0);
    // harden: this wave's ds_reads retired before the trailing barrier (region
    // handoff to next phase's staging is then architecturally safe).
    asm volatile("s_waitcnt lgkmcnt(0)" ::: "memory");
}

// One iteration = 2 K-tiles (T even: buf0, T+1: buf1), 8 phases.
// Staging schedule (unit written strictly after the trailing barrier of its
// last reader; read only after a counted-vmcnt + barrier publication):
//   P1:U(T+1,A,kh1) P2:U(T+1,B,kh1) P3:U(T+2,A,kh0) P4:U(T+2,B,kh0)+vmcnt(4)
//   P5:U(T+2,A,kh1) P6:U(T+2,B,kh1) P7:U(T+3,A,kh0) P8:U(T+3,B,kh0)+vmcnt(4)
// vmcnt(4) @P4 => landed through P2's unit: covers P5 (staged prev P7/P8) and P7 (staged P1/P2).
// vmcnt(4) @P8 => landed through P6's unit: covers next-iter P1 and P3 reads.
template<bool FULL>
__device__ __forceinline__ void ktile_pair(const bf16* __restrict__ A, const bf16* __restrict__ W,
                                           char* lds, int T, int m0, int n0,
                                           int w, int l, int wr, int wc, f4 (&acc)[8][4]) {
    short8 af[4], bf[4];
    // ---- P1: tile T kk0, mf0-3 ----
    read_b4(bf, lds + 32768, wc, l);
    read_a4(af, lds + 0, wr, 0, l);
    stage_unit(A, m0, lds + 81920, (T + 1) * 64 + 32, w, l);
    pbar(); mfma16<0>(af, bf, acc); pbar();
    // ---- P2: tile T kk0, mf4-7 ----
    read_a4(af, lds + 0, wr, 4, l);
    stage_unit(W, n0, lds + 114688, (T + 1) * 64 + 32, w, l);
    pbar(); mfma16<4>(af, bf, acc); pbar();
    // ---- P3: tile T kk1, mf0-3 ----
    read_b4(bf, lds + 49152, wc, l);
    read_a4(af, lds + 16384, wr, 0, l);
    if constexpr (FULL) stage_unit(A, m0, lds + 0, (T + 2) * 64, w, l);
    pbar(); mfma16<0>(af, bf, acc); pbar();
    // ---- P4: tile T kk1, mf4-7 ----
    read_a4(af, lds + 16384, wr, 4, l);
    if constexpr (FULL) {
        stage_unit(W, n0, lds + 32768, (T + 2) * 64, w, l);
        asm volatile("s_waitcnt vmcnt(4)" ::: "memory");
    } else {
        asm volatile("s_waitcnt vmcnt(0)" ::: "memory");
    }
    pbar(); mfma16<4>(af, bf, acc); pbar();
    // ---- P5: tile T+1 kk0, mf0-3 ----
    read_b4(bf, lds + 98304, wc, l);
    read_a4(af, lds + 65536, wr, 0, l);
    if constexpr (FULL) stage_unit(A, m0, lds + 16384, (T + 2) * 64 + 32, w, l);
    pbar(); mfma16<0>(af, bf, acc); pbar();
    // ---- P6: tile T+1 kk0, mf4-7 ----
    read_a4(af, lds + 65536, wr, 4, l);
    if constexpr (FULL) stage_unit(W, n0, lds + 49152, (T + 2) * 64 + 32, w, l);
    pbar(); mfma16<4>(af, bf, acc); pbar();
    // ---- P7: tile T+1 kk1, mf0-3 ----
    read_b4(bf, lds + 114688, wc, l);
    read_a4(af, lds + 81920, wr, 0, l);
    if constexpr (FULL) stage_unit(A, m0, lds + 65536, (T + 3) * 64, w, l);
    pbar(); mfma16<0>(af, bf, acc); pbar();
    // ---- P8: tile T+1 kk1, mf4-7 ----
    read_a4(af, lds + 81920, wr, 4, l);
    if constexpr (FULL) {
        stage_unit(W, n0, lds + 98304, (T + 3) * 64, w, l);
        asm volatile("s_waitcnt vmcnt(4)" ::: "memory");
    } else {
        asm volatile("s_waitcnt vmcnt(0)" ::: "memory");
    }
    pbar(); mfma16<4>(af, bf, acc); pbar();
}

__global__ __launch_bounds__(512, 2)
void gemm256(const bf16* __restrict__ A, const bf16* __restrict__ Wz, const bf16* __restrict__ Wh,
             const float* __restrict__ bz, const float* __restrict__ bh,
             fp16* __restrict__ kout, fp16* __restrict__ pout) {
    __shared__ __attribute__((aligned(16))) char lds[131072];
    const int t = threadIdx.x;
    const int l = t & 63, w = t >> 6;
    const int wr = w >> 2, wc = w & 3;

    // XCD-bijective swizzle (1024 blocks, %8==0). widx decode: 8 consecutive
    // work-items = same m-tile x {both gemms} x {4 n-tiles} -> each XCD owns
    // disjoint m-tiles (A fetched once) + both W matrices (4MB, L2-resident).
    const int bid = blockIdx.x;
    const int widx = (bid & 7) * 128 + (bid >> 3);
    const int m_idx = widx >> 3;
    const int gsel = (widx >> 2) & 1;
    const int n_idx = widx & 3;
    const bf16* W = gsel ? Wh : Wz;
    const float* bias = gsel ? bh : bz;
    fp16* out = gsel ? pout : kout;
    const int m0 = m_idx * 256, n0 = n_idx * 256;

    f4 acc[8][4];
#pragma unroll
    for (int i = 0; i < 8; i++)
#pragma unroll
        for (int j = 0; j < 4; j++) acc[i][j] = (f4)(0.f);

    // prologue: 6 units (tile0 all 4, tile1 kh0 pair); vmcnt(4) => tile0 landed.
    stage_unit(A, m0, lds + 0,     0,  w, l);
    stage_unit(W, n0, lds + 32768, 0,  w, l);
    stage_unit(A, m0, lds + 16384, 32, w, l);
    stage_unit(W, n0, lds + 49152, 32, w, l);
    stage_unit(A, m0, lds + 65536, 64, w, l);
    stage_unit(W, n0, lds + 98304, 64, w, l);
    asm volatile("s_waitcnt vmcnt(4)" ::: "memory");
    pbar();

#pragma unroll 1
    for (int it = 0; it < 7; ++it)
        ktile_pair<true>(A, W, lds, 2 * it, m0, n0, w, l, wr, wc, acc);
    ktile_pair<false>(A, W, lds, 14, m0, n0, w, l, wr, wc, acc);

    // epilogue: bias add, fp16 store. C/D: col=lane&15, row=(lane>>4)*4+reg.
    const int col16 = l & 15, quad = l >> 4;
#pragma unroll
    for (int nf = 0; nf < 4; nf++) {
        const int cg = n0 + wc * 64 + nf * 16 + col16;
        const float bv = bias[cg];
#pragma unroll
        for (int mf = 0; mf < 8; mf++) {
#pragma unroll
            for (int r = 0; r < 4; r++) {
                const int rg = m0 + wr * 128 + mf * 16 + quad * 4 + r;
                out[(size_t)rg * DH + cg] = (fp16)(acc[mf][nf][r] + bv);
            }
        }
    }
}

// ---------------- linear-space gates ----------------
__device__ __forceinline__ void gates_lin(float kv, float pv, float& a, float& b) {
    float ek = __expf(-kv);
    float z = __builtin_amdgcn_rcpf(1.f + ek);
    a = 1.f - z;
    float ep = __expf(-pv);
    float gneg = __builtin_amdgcn_rcpf(1.f + ep);
    float g = (pv >= 0.f) ? (pv + 0.5f) : gneg;
    b = z * g;
}

// ---------------- pass 1: per-(b,chunk,h-quad) affine composite ----------------
__global__ void scan_pass1(const fp16* __restrict__ kbuf, const fp16* __restrict__ pbuf,
                           float* __restrict__ cla, float* __restrict__ clb) {
    const int tid = blockIdx.x * 256 + threadIdx.x;
    const int hq = tid & 255;
    const int c = (tid >> 8) & 127;
    const int b = tid >> 15;
    size_t base = ((size_t)b * SS + (size_t)c * CL) * DH + hq * 4;

    float A[4] = {1.f, 1.f, 1.f, 1.f};
    float Bc[4] = {0.f, 0.f, 0.f, 0.f};
#pragma unroll 4
    for (int tt = 0; tt < CL; tt++) {
        size_t idx = base + (size_t)tt * DH;
        h4 k4 = *(const h4*)(kbuf + idx);
        h4 p4 = *(const h4*)(pbuf + idx);
#pragma unroll
        for (int q = 0; q < 4; q++) {
            float a, bb;
            gates_lin((float)k4[q], (float)p4[q], a, bb);
            A[q] *= a;
            Bc[q] = fmaf(a, Bc[q], bb);
        }
    }
    const size_t ci = (size_t)(b * NC + c) * DH + hq * 4;
    *(f4*)(cla + ci) = *(f4*)A;
    *(f4*)(clb + ci) = *(f4*)Bc;
}

// ---------------- pass 2: sequential scan over chunk summaries ----------------
__global__ void scan_pass2(const float* __restrict__ cla, const float* __restrict__ clb,
                           float* __restrict__ car) {
    const int tid = blockIdx.x * 256 + threadIdx.x;
    const int b = tid >> 10;
    const int h = tid & 1023;
    float carry = 0.5f;
#pragma unroll 8
    for (int c = 0; c < NC; c++) {
        const size_t ci = (size_t)(b * NC + c) * DH + h;
        car[ci] = carry;
        carry = fmaf(cla[ci], carry, clb[ci]);
    }
}

// ---------------- pass 3: apply within chunk, write h ----------------
__global__ void scan_pass3(const fp16* __restrict__ kbuf, const fp16* __restrict__ pbuf,
                           const float* __restrict__ car, float* __restrict__ out) {
    const int tid = blockIdx.x * 256 + threadIdx.x;
    const int hq = tid & 255;
    const int c = (tid >> 8) & 127;
    const int b = tid >> 15;
    size_t base = ((size_t)b * SS + (size_t)c * CL) * DH + hq * 4;

    const size_t ci = (size_t)(b * NC + c) * DH + hq * 4;
    f4 car4 = *(const f4*)(car + ci);
    float h[4] = {car4[0], car4[1], car4[2], car4[3]};
#pragma unroll 4
    for (int tt = 0; tt < CL; tt++) {
        size_t idx = base + (size_t)tt * DH;
        h4 k4 = *(const h4*)(kbuf + idx);
        h4 p4 = *(const h4*)(pbuf + idx);
        f4 o;
#pragma unroll
        for (int q = 0; q < 4; q++) {
            float a, bb;
            gates_lin((float)k4[q], (float)p4[q], a, bb);
            h[q] = fmaf(a, h[q], bb);
            o[q] = h[q];
        }
        *(f4*)(out + idx) = o;
    }
}

// ---------------- launch ----------------
extern "C" void kernel_launch(void* const* d_in, const int* in_sizes, int n_in,
                              void* d_out, int out_size, void* d_ws, size_t ws_size,
                              hipStream_t stream) {
    const float* x  = (const float*)d_in[0];
    const float* Wz = (const float*)d_in[1];
    const float* bz = (const float*)d_in[2];
    const float* Wh = (const float*)d_in[3];
    const float* bh = (const float*)d_in[4];

    char* ws = (char*)d_ws;
    bf16* xb   = (bf16*)(ws + OFF_XB);
    bf16* wzb  = (bf16*)(ws + OFF_WZB);
    bf16* whb  = (bf16*)(ws + OFF_WHB);
    fp16* kbuf = (fp16*)(ws + OFF_K);
    fp16* pbuf = (fp16*)(ws + OFF_P);
    float* cla  = (float*)(ws + OFF_CLA);
    float* clb  = (float*)(ws + OFF_CLB);
    float* car  = (float*)(ws + OFF_CAR);
    float* out  = (float*)d_out;

    convert_kernel<<<17408, 256, 0, stream>>>(x, Wz, Wh, xb, wzb, whb);

    // both GEMMs: 128 m-tiles x 4 n-tiles x 2 = 1024 blocks of 512
    gemm256<<<1024, 512, 0, stream>>>(xb, wzb, whb, bz, bh, kbuf, pbuf);

    scan_pass1<<<(BB * NC * 256) / 256, 256, 0, stream>>>(kbuf, pbuf, cla, clb);
    scan_pass2<<<(BB * DH) / 256, 256, 0, stream>>>(cla, clb, car);
    scan_pass3<<<(BB * NC * 256) / 256, 256, 0, stream>>>(kbuf, pbuf, car, out);
}